// Round 13
// baseline (276.449 us; speedup 1.0000x reference)
//
#include <hip/hip_runtime.h>

#define B_   32
#define L_   1024
#define CD_  256
#define ZD_  256
#define P_   12
#define NEG_ 8
#define TL_  32    // l-rows per block

typedef __attribute__((ext_vector_type(8))) short bf16x8;
typedef __attribute__((ext_vector_type(4))) float f32x4;
typedef __attribute__((ext_vector_type(4))) int   i32x4;

// LDS (dynamic, 32KB total):
//   [0,32768)  c-tile f32 staging (one-time, row-XOR swizzled via pre-XOR'd src)
//   after cf extraction the region is reused:
//   [0,16384)  Wc (32 rows x 512B bf16, row-XOR swz)
//   [16384,17152) pbuf: pbm[3][32], pbs[3][32]
#define LDS_TOTAL 32768
#define PB_OFF    16384

#define SCC  (127.0f / 4.2f)                      // c int8 quant scale
#define FDQ  ((1.0f / 127.0f) * (4.2f / 127.0f)) // dequant for acc

__device__ __forceinline__ unsigned short f2b(float f) {
    unsigned u = __float_as_uint(f);
    u += 0x7FFFu + ((u >> 16) & 1u);              // round-nearest-even
    return (unsigned short)(u >> 16);
}

__device__ __forceinline__ void glds16(const void* g, void* l) {
    __builtin_amdgcn_global_load_lds(
        (const __attribute__((address_space(1))) unsigned int*)g,
        (__attribute__((address_space(3))) unsigned int*)l, 16, 0, 0);
}

// ws: ws[0]=loss, ws[1]=msum; Wi8 @byte 256: frag-major [p][kk4][hi][d][16B] i8
__global__ __launch_bounds__(256) void cnce_prep(
        const float* __restrict__ W, signed char* __restrict__ Wi8,
        const int* __restrict__ length, float* __restrict__ ws) {
    const int blk = blockIdx.x;
    const int tid = threadIdx.x;
    if (blk < 192) {
        const int p = blk >> 4, kk4 = (blk >> 2) & 3, hig = blk & 3;
        unsigned wds[4];
        #pragma unroll
        for (int qq = 0; qq < 4; ++qq) {
            unsigned u = 0;
            #pragma unroll
            for (int e = 0; e < 4; ++e) {
                int cc = kk4 * 64 + hig * 16 + qq * 4 + e;
                int q = (int)(W[((size_t)p * CD_ + cc) * ZD_ + tid] * 127.f + 0.5f);
                u |= ((unsigned)(q & 255)) << (8 * e);
            }
            wds[qq] = u;
        }
        *(int4*)(Wi8 + ((size_t)blk * 256 + tid) * 16) = *(const int4*)wds;
    } else {
        if (tid < 64) {
            int v = (tid < B_) ? length[tid] : 0;
            #pragma unroll
            for (int mm = 1; mm < 64; mm <<= 1) v += __shfl_xor(v, mm);
            if (tid == 0) { ws[0] = 0.f; ws[1] = (float)v; }
        }
    }
}

__global__ __launch_bounds__(512, 2) void cnce_main(
        const float* __restrict__ c, const float* __restrict__ z,
        const signed char* __restrict__ Wi8,
        const int* __restrict__ neg_shift,
        const int* __restrict__ length, float* __restrict__ ws) {
    extern __shared__ char smem[];
    char* wcb = smem;                       // Wc after c-stage dies
    float* pbm = (float*)(smem + PB_OFF);
    float* pbs = pbm + 96;

    // XCD swizzle: 1024 blocks = 8 XCD x 128; XCD k gets b in [4k,4k+4)
    const int hbx  = blockIdx.x;
    const int work = ((hbx & 7) << 7) | (hbx >> 3);
    const int b  = work >> 5;
    const int l0 = (work & 31) * TL_;
    const int tid  = threadIdx.x;
    const int w    = tid >> 6;          // 0..7
    const int lane = tid & 63;
    const int hi   = lane >> 4;
    const int m    = lane & 15;
    const int rg   = w & 1;             // row-group: rows rg*16+m
    const int jg   = w >> 1;            // 0:{pos,n0,n1} 1:{n2,n3} 2:{n4,n5} 3:{n6,n7}

    int sh8[NEG_];
    #pragma unroll
    for (int j = 0; j < NEG_; ++j) sh8[j] = neg_shift[j];
    const int len_b = length[b];
    const bool owner = (hi == (m >> 2));
    const int  rsel  = m & 3;
    const int  l     = rg * 16 + m;     // phase-B row within tile
    const int  gl    = l0 + l;

    // ---- stage c f32 into smem[0,32768) (linear dest, src col pre-XOR'd) ----
    {
        const char* cb = (const char*)(c + (size_t)(b * L_ + l0) * CD_);
        #pragma unroll
        for (int i = 0; i < 4; ++i) {
            int f = i * 8192 + w * 1024 + (lane << 4);
            int row = f >> 10, col = f & 1023;
            glds16(cb + ((size_t)row << 10) + (col ^ ((row & 7) << 4)),
                   smem + i * 8192 + w * 1024);
        }
    }
    __syncthreads();

    // ---- c fragments -> int8 (MFMA B-operand), registers ----
    i32x4 cf[4][2];
    #pragma unroll
    for (int kk4 = 0; kk4 < 4; ++kk4)
        #pragma unroll
        for (int ni = 0; ni < 2; ++ni) {
            int lr = ni * 16 + m;
            int cb0 = kk4 * 256 + hi * 64;          // f32 byte offset in 1024B row
            unsigned wd[4];
            #pragma unroll
            for (int qq = 0; qq < 4; ++qq) {
                float4 v = *(const float4*)(smem + lr * 1024 + ((cb0 + qq * 16) ^ ((lr & 7) << 4)));
                int q0 = (int)rintf(fminf(fmaxf(v.x * SCC, -127.f), 127.f));
                int q1 = (int)rintf(fminf(fmaxf(v.y * SCC, -127.f), 127.f));
                int q2 = (int)rintf(fminf(fmaxf(v.z * SCC, -127.f), 127.f));
                int q3 = (int)rintf(fminf(fmaxf(v.w * SCC, -127.f), 127.f));
                wd[qq] = (q0 & 255) | ((q1 & 255) << 8) | ((q2 & 255) << 16) | ((q3 & 255) << 24);
            }
            cf[kk4][ni] = *(const i32x4*)wd;
        }

    // ---- p-invariant negative z-row fragments into REGISTERS (reused 12x) ----
    const float* zbF = z + (size_t)b * L_ * ZD_;
    const int winA = jg ? 2 * jg : 0;
    const int zra = (gl + sh8[winA]) & (L_ - 1);
    const int zrb = (gl + sh8[winA + 1]) & (L_ - 1);
    bf16x8 zrA[8], zrB[8];
    #pragma unroll
    for (int kk = 0; kk < 8; ++kk) {
        const float* pa = zbF + (size_t)zra * ZD_ + kk * 32 + hi * 8;
        const float* pb = zbF + (size_t)zrb * ZD_ + kk * 32 + hi * 8;
        float4 a0 = *(const float4*)pa, a1 = *(const float4*)(pa + 4);
        float4 b0 = *(const float4*)pb, b1 = *(const float4*)(pb + 4);
        unsigned short ha[8] = { f2b(a0.x), f2b(a0.y), f2b(a0.z), f2b(a0.w),
                                 f2b(a1.x), f2b(a1.y), f2b(a1.z), f2b(a1.w) };
        unsigned short hb[8] = { f2b(b0.x), f2b(b0.y), f2b(b0.z), f2b(b0.w),
                                 f2b(b1.x), f2b(b1.y), f2b(b1.z), f2b(b1.w) };
        zrA[kk] = *(const bf16x8*)ha;
        zrB[kk] = *(const bf16x8*)hb;
    }
    __syncthreads();   // c region dead; Wc may now overwrite

    i32x4 acc[2][2];
    auto do_gemm = [&](int p) {
        #pragma unroll
        for (int mi = 0; mi < 2; ++mi)
            #pragma unroll
            for (int ni = 0; ni < 2; ++ni) acc[mi][ni] = (i32x4){0, 0, 0, 0};
        const signed char* wp = Wi8 + (size_t)p * 65536;
        #pragma unroll
        for (int kk4 = 0; kk4 < 4; ++kk4) {
            const signed char* sl = wp + (kk4 * 4 + hi) * 4096;
            i32x4 wf0 = *(const i32x4*)(sl + (w * 32 + m) * 16);
            i32x4 wf1 = *(const i32x4*)(sl + (w * 32 + 16 + m) * 16);
            acc[0][0] = __builtin_amdgcn_mfma_i32_16x16x64_i8(wf0, cf[kk4][0], acc[0][0], 0, 0, 0);
            acc[0][1] = __builtin_amdgcn_mfma_i32_16x16x64_i8(wf0, cf[kk4][1], acc[0][1], 0, 0, 0);
            acc[1][0] = __builtin_amdgcn_mfma_i32_16x16x64_i8(wf1, cf[kk4][0], acc[1][0], 0, 0, 0);
            acc[1][1] = __builtin_amdgcn_mfma_i32_16x16x64_i8(wf1, cf[kk4][1], acc[1][1], 0, 0, 0);
        }
    };
    auto do_spill = [&]() {
        #pragma unroll
        for (int mi = 0; mi < 2; ++mi)
            #pragma unroll
            for (int ni = 0; ni < 2; ++ni) {
                int lr = ni * 16 + m;
                int d0 = w * 32 + mi * 16 + hi * 4;
                unsigned short hh[4] = { f2b((float)acc[mi][ni][0] * FDQ),
                                         f2b((float)acc[mi][ni][1] * FDQ),
                                         f2b((float)acc[mi][ni][2] * FDQ),
                                         f2b((float)acc[mi][ni][3] * FDQ) };
                *(uint2*)(wcb + ((lr * 512 + d0 * 2) ^ ((lr & 15) << 4))) = *(const uint2*)hh;
            }
    };

    float lsum = 0.f;
    do_gemm(0);
    do_spill();
    __syncthreads();

    for (int p = 0; p < P_; ++p) {
        if (p < P_ - 1) do_gemm(p + 1);      // overlaps with phase-B below
        // ---- phase B(p): pav from LDS, z from registers ----
        bf16x8 pav[8];
        #pragma unroll
        for (int kk = 0; kk < 8; ++kk)
            pav[kk] = *(const bf16x8*)(wcb + ((l * 512 + kk * 64 + hi * 16) ^ ((l & 15) << 4)));

        f32x4 eA = {0,0,0,0}, oA = {0,0,0,0}, eB = {0,0,0,0}, oB = {0,0,0,0};
        #pragma unroll
        for (int kk = 0; kk < 8; kk += 2) {
            eA = __builtin_amdgcn_mfma_f32_16x16x32_bf16(pav[kk],     zrA[kk],     eA, 0, 0, 0);
            oA = __builtin_amdgcn_mfma_f32_16x16x32_bf16(pav[kk + 1], zrA[kk + 1], oA, 0, 0, 0);
            eB = __builtin_amdgcn_mfma_f32_16x16x32_bf16(pav[kk],     zrB[kk],     eB, 0, 0, 0);
            oB = __builtin_amdgcn_mfma_f32_16x16x32_bf16(pav[kk + 1], zrB[kk + 1], oB, 0, 0, 0);
        }
        float scA = (rsel == 0) ? eA[0] + oA[0] : (rsel == 1) ? eA[1] + oA[1]
                  : (rsel == 2) ? eA[2] + oA[2] : eA[3] + oA[3];
        float scB = (rsel == 0) ? eB[0] + oB[0] : (rsel == 1) ? eB[1] + oB[1]
                  : (rsel == 2) ? eB[2] + oB[2] : eB[3] + oB[3];
        float scP = -3e38f;
        if (jg == 0) {                       // positive: f32 z, convert on the fly
            const int rowz = (gl + p + 1) & (L_ - 1);
            const float* zr = zbF + (size_t)rowz * ZD_ + hi * 8;
            f32x4 e = {0,0,0,0}, o = {0,0,0,0};
            #pragma unroll
            for (int kk = 0; kk < 8; ++kk) {
                float4 z0 = *(const float4*)(zr + kk * 32);
                float4 z1 = *(const float4*)(zr + kk * 32 + 4);
                unsigned short hh[8] = { f2b(z0.x), f2b(z0.y), f2b(z0.z), f2b(z0.w),
                                         f2b(z1.x), f2b(z1.y), f2b(z1.z), f2b(z1.w) };
                bf16x8 bz = *(const bf16x8*)hh;
                if (kk & 1) o = __builtin_amdgcn_mfma_f32_16x16x32_bf16(pav[kk], bz, o, 0, 0, 0);
                else        e = __builtin_amdgcn_mfma_f32_16x16x32_bf16(pav[kk], bz, e, 0, 0, 0);
            }
            scP = (rsel == 0) ? e[0] + o[0] : (rsel == 1) ? e[1] + o[1]
                : (rsel == 2) ? e[2] + o[2] : e[3] + o[3];
        }
        // partial logsumexp
        float mx, se;
        if (jg == 0) {
            mx = fmaxf(fmaxf(scP, scA), scB);
            se = __expf(scP - mx) + __expf(scA - mx) + __expf(scB - mx);
        } else {
            mx = fmaxf(scA, scB);
            se = __expf(scA - mx) + __expf(scB - mx);
            if (owner) { pbm[(jg - 1) * 32 + l] = mx; pbs[(jg - 1) * 32 + l] = se; }
        }
        __syncthreads();
        if (jg == 0) {
            float M = mx, S = se;
            #pragma unroll
            for (int q = 0; q < 3; ++q) {
                float pm = pbm[q * 32 + l], ps = pbs[q * 32 + l];
                float M2 = fmaxf(M, pm);
                S = S * __expf(M - M2) + ps * __expf(pm - M2);
                M = M2;
            }
            if (owner && gl < len_b) lsum += __logf(S) + M - scP;
        }
        if (p < P_ - 1) do_spill();
        __syncthreads();
    }

    if (jg == 0) {
        #pragma unroll
        for (int sh = 1; sh < 64; sh <<= 1) lsum += __shfl_xor(lsum, sh);
        if (lane == 0) atomicAdd(&ws[0], lsum);
    }
}

__global__ void cnce_fin(const float* __restrict__ ws, float* __restrict__ out) {
    out[0] = ws[0] / ws[1];
}

extern "C" void kernel_launch(void* const* d_in, const int* in_sizes, int n_in,
                              void* d_out, int out_size, void* d_ws, size_t ws_size,
                              hipStream_t stream) {
    const float* c  = (const float*)d_in[0];
    const float* z  = (const float*)d_in[1];
    const float* W  = (const float*)d_in[2];
    const int* neg_shift = (const int*)d_in[3];
    const int* length    = (const int*)d_in[4];
    float* out = (float*)d_out;
    float* ws  = (float*)d_ws;
    signed char* Wi8 = (signed char*)((char*)d_ws + 256);

    (void)hipFuncSetAttribute((const void*)cnce_main,
                              hipFuncAttributeMaxDynamicSharedMemorySize, LDS_TOTAL);

    cnce_prep<<<193, 256, 0, stream>>>(W, Wi8, length, ws);
    cnce_main<<<1024, 512, LDS_TOTAL, stream>>>(c, z, Wi8, neg_shift, length, ws);
    cnce_fin<<<1, 1, 0, stream>>>(ws, out);
}